// Round 5
// baseline (170.742 us; speedup 1.0000x reference)
//
#include <hip/hip_runtime.h>
#include <stdint.h>

#define NBINS 256
#define HW    (512 * 512)
#define NIMG  64
#define MMB   64   // minmax blocks per image (4 tiles each)
#define HB    32   // hist blocks per image (8 tiles each)
#define RB 0
#define GB 1032
#define BB 2064
#define STW 3096   // SoA staging words per buffer

// f64 grayscale, exact op order verified bit-exact vs np reference (rounds 3-4):
__device__ __forceinline__ double gray_of(float r, float g, float b) {
    return fma((double)b, (double)0.1140f,
           fma((double)g, (double)0.5870f,
               (double)r * (double)0.2989f));
}

// Stage one 1024-px tile (768 float4, fully lane-coalesced loads) into SoA LDS.
__device__ __forceinline__ void stage3(const float4* __restrict__ xv, int64_t tile4,
                                       float* __restrict__ st, int tid) {
    #pragma unroll
    for (int k = 0; k < 3; ++k) {
        const int q = k * 256 + tid;
        const float4 v = xv[tile4 + q];
        const int f0 = q * 4;
        int p = (int)(((unsigned)f0 * 21846u) >> 16);  // f0/3
        int c = f0 - 3 * p;                            // f0%3
        const float e[4] = {v.x, v.y, v.z, v.w};
        #pragma unroll
        for (int j = 0; j < 4; ++j) {
            const int base = (c == 0) ? RB : ((c == 1) ? GB : BB);
            st[base + p] = e[j];
            if (++c == 3) { c = 0; ++p; }
        }
    }
}

// 64 blocks/img x 4 tiles; per-block min/max partials (no atomics, no init)
__global__ __launch_bounds__(256) void k_minmax(const float* __restrict__ x,
                                                double* __restrict__ mm_part) {
    __shared__ float st[2][STW];
    __shared__ double smn[4], smx[4];
    const int tid = threadIdx.x;
    const int img = blockIdx.x >> 6;
    const int blk = blockIdx.x & 63;
    const int64_t img4 = (int64_t)img * (HW * 3 / 4);
    const float4* xv = (const float4*)x;
    double mn = 1e300, mx = -1e300;
    stage3(xv, img4 + (int64_t)(blk * 4) * 768, st[0], tid);
    for (int it = 0; it < 4; ++it) {
        __syncthreads();   // buf[it&1] staged; prior reads of this buf done 2 iters ago
        if (it < 3) stage3(xv, img4 + (int64_t)(blk * 4 + it + 1) * 768, st[(it + 1) & 1], tid);
        const float* s = st[it & 1];
        const float4 R = *(const float4*)&s[RB + 4 * tid];
        const float4 G = *(const float4*)&s[GB + 4 * tid];
        const float4 B = *(const float4*)&s[BB + 4 * tid];
        const double g0 = gray_of(R.x, G.x, B.x), g1 = gray_of(R.y, G.y, B.y),
                     g2 = gray_of(R.z, G.z, B.z), g3 = gray_of(R.w, G.w, B.w);
        mn = fmin(mn, fmin(fmin(g0, g1), fmin(g2, g3)));
        mx = fmax(mx, fmax(fmax(g0, g1), fmax(g2, g3)));
    }
    #pragma unroll
    for (int off = 32; off; off >>= 1) {
        mn = fmin(mn, __shfl_xor(mn, off));
        mx = fmax(mx, __shfl_xor(mx, off));
    }
    if ((tid & 63) == 0) { smn[tid >> 6] = mn; smx[tid >> 6] = mx; }
    __syncthreads();
    if (tid == 0) {
        mn = fmin(fmin(smn[0], smn[1]), fmin(smn[2], smn[3]));
        mx = fmax(fmax(smx[0], smx[1]), fmax(smx[2], smx[3]));
        mm_part[(img * MMB + blk) * 2 + 0] = mn;
        mm_part[(img * MMB + blk) * 2 + 1] = mx;
    }
}

// wave-0 reduce of the 64 min/max partials (exact; order-insensitive)
__device__ __forceinline__ void mm_reduce(const double* __restrict__ mm_part, int img,
                                          int tid, double* __restrict__ sdm) {
    if (tid < 64) {
        double mn = mm_part[(img * MMB + tid) * 2 + 0];
        double mx = mm_part[(img * MMB + tid) * 2 + 1];
        #pragma unroll
        for (int off = 32; off; off >>= 1) {
            mn = fmin(mn, __shfl_xor(mn, off));
            mx = fmax(mx, __shfl_xor(mx, off));
        }
        if (tid == 0) { sdm[0] = mn; sdm[1] = mx; }
    }
}

// 32 blocks/img x 8 tiles: histogram partials + packed u8 bin-index emit
template <bool WIDX>
__global__ __launch_bounds__(256) void k_hist(const float* __restrict__ x,
        const double* __restrict__ mm_part,
        unsigned* __restrict__ hist_part, unsigned* __restrict__ idx4) {
    __shared__ float st[2][STW];
    __shared__ unsigned lh[NBINS];
    __shared__ double sdm[2];
    const int tid = threadIdx.x;
    const int img = blockIdx.x >> 5;
    const int blk = blockIdx.x & 31;
    lh[tid] = 0u;
    mm_reduce(mm_part, img, tid, sdm);
    const int64_t img4 = (int64_t)img * (HW * 3 / 4);
    const float4* xv = (const float4*)x;
    stage3(xv, img4 + (int64_t)(blk * 8) * 768, st[0], tid);
    __syncthreads();   // buf0 + lh + sdm ready
    const double mn = sdm[0];
    const double scale = 256.0 / fmax(__dsub_rn(sdm[1], mn), 1e-12);
    for (int it = 0; it < 8; ++it) {
        if (it < 7) stage3(xv, img4 + (int64_t)(blk * 8 + it + 1) * 768, st[(it + 1) & 1], tid);
        const float* s = st[it & 1];
        const float4 R = *(const float4*)&s[RB + 4 * tid];
        const float4 G = *(const float4*)&s[GB + 4 * tid];
        const float4 B = *(const float4*)&s[BB + 4 * tid];
        const double g[4] = {gray_of(R.x, G.x, B.x), gray_of(R.y, G.y, B.y),
                             gray_of(R.z, G.z, B.z), gray_of(R.w, G.w, B.w)};
        unsigned pack = 0;
        #pragma unroll
        for (int j = 0; j < 4; ++j) {
            int id = (int)__dmul_rn(__dsub_rn(g[j], mn), scale);  // trunc = astype(int32)
            id = id < 0 ? 0 : (id > 255 ? 255 : id);
            atomicAdd(&lh[id], 1u);
            pack |= (unsigned)id << (8 * j);
        }
        if (WIDX) idx4[img * (HW / 4) + (blk * 8 + it) * 256 + tid] = pack;
        __syncthreads();   // next buf staged; reads of cur buf done; (last iter: covers lh)
    }
    hist_part[(img * HB + blk) * NBINS + tid] = lh[tid];
}

// one 256-thread block per image; integer partial-sum + bit-exact serial f64 Otsu
__global__ void k_otsu(const unsigned* __restrict__ hist_part,
                       const double* __restrict__ mm_part,
                       double* __restrict__ thr, int* __restrict__ bidx) {
    __shared__ double h[NBINS], w2s[NBINS], m2s[NBINS], vv[NBINS];
    __shared__ double sdm[2];
    const int img = blockIdx.x, t = threadIdx.x;
    mm_reduce(mm_part, img, t, sdm);
    unsigned hu = 0;
    for (int b = 0; b < HB; ++b) hu += hist_part[(img * HB + b) * NBINS + t];  // exact int sum
    h[t] = (double)hu;
    __syncthreads();
    const double mn   = sdm[0];
    const double rng  = fmax(__dsub_rn(sdm[1], mn), 1e-12);
    const double step = rng / 256.0;
    double w1 = 0.0, hc1 = 0.0;
    for (int j = 0; j <= t; ++j) {
        const double c = __dadd_rn(mn, __dmul_rn((double)j + 0.5, step));
        w1  = __dadd_rn(w1, h[j]);
        hc1 = __dadd_rn(hc1, __dmul_rn(h[j], c));
    }
    const double m1 = hc1 / fmax(w1, 1e-12);
    double w2 = 0.0, hc2 = 0.0;
    for (int j = NBINS - 1; j >= t; --j) {
        const double c = __dadd_rn(mn, __dmul_rn((double)j + 0.5, step));
        w2  = __dadd_rn(w2, h[j]);
        hc2 = __dadd_rn(hc2, __dmul_rn(h[j], c));
    }
    w2s[t] = w2;
    m2s[t] = hc2 / fmax(w2, 1e-12);
    __syncthreads();
    if (t < NBINS - 1) {
        const double d = __dsub_rn(m1, m2s[t + 1]);
        vv[t] = __dmul_rn(__dmul_rn(w1, w2s[t + 1]), __dmul_rn(d, d));
    }
    __syncthreads();
    if (t == 0) {
        double best = -1.0; int bi = 0;
        for (int i = 0; i < NBINS - 1; ++i)
            if (vv[i] > best) { best = vv[i]; bi = i; }   // first-occurrence argmax
        thr[img]  = __dadd_rn(mn, __dmul_rn((double)bi + 0.5, step));
        bidx[img] = bi;
    }
}

// 64 blocks/img x 4 tiles: binarize + channel-replicate, pure-register, no LDS
template <bool UIDX>
__global__ __launch_bounds__(256) void k_binarize(const float* __restrict__ x,
        const unsigned* __restrict__ idx4,
        const double* __restrict__ thr, const int* __restrict__ bidx,
        float* __restrict__ out) {
    __shared__ float st[2][STW];     // only used when !UIDX
    const int tid = threadIdx.x;
    const int img = blockIdx.x >> 6;
    const int blk = blockIdx.x & 63;
    const double T = thr[img];
    const int bi = UIDX ? bidx[img] : 0;
    const int64_t img4 = (int64_t)img * (HW * 3 / 4);
    const float4* xv = (const float4*)x;
    float4* ov = (float4*)out;
    if (!UIDX) stage3(xv, img4 + (int64_t)(blk * 4) * 768, st[0], tid);
    for (int it = 0; it < 4; ++it) {
        const int tl = blk * 4 + it;
        float bb[4];
        if (UIDX) {
            const unsigned pk = idx4[img * (HW / 4) + tl * 256 + tid];
            #pragma unroll
            for (int j = 0; j < 4; ++j) {
                const int id = (pk >> (8 * j)) & 255;
                float r;
                if (id > bi)      r = 255.f;
                else if (id < bi) r = 0.f;
                else {  // rare (~0.4%): boundary bin, recompute exact gray
                    const int64_t p = (int64_t)img * HW + (int64_t)tl * 1024 + 4 * tid + j;
                    const double g = gray_of(x[3 * p], x[3 * p + 1], x[3 * p + 2]);
                    r = (g > T) ? 255.f : 0.f;
                }
                bb[j] = r;
            }
        } else {
            __syncthreads();
            if (it < 3) stage3(xv, img4 + (int64_t)(blk * 4 + it + 1) * 768, st[(it + 1) & 1], tid);
            const float* s = st[it & 1];
            const float4 R = *(const float4*)&s[RB + 4 * tid];
            const float4 G = *(const float4*)&s[GB + 4 * tid];
            const float4 B = *(const float4*)&s[BB + 4 * tid];
            bb[0] = (gray_of(R.x, G.x, B.x) > T) ? 255.f : 0.f;
            bb[1] = (gray_of(R.y, G.y, B.y) > T) ? 255.f : 0.f;
            bb[2] = (gray_of(R.z, G.z, B.z) > T) ? 255.f : 0.f;
            bb[3] = (gray_of(R.w, G.w, B.w) > T) ? 255.f : 0.f;
        }
        // thread's 3 float4 outputs cover exactly its own 4 pixels -> in-register replicate
        const int64_t ob = img4 + (int64_t)tl * 768 + 3 * tid;
        ov[ob + 0] = make_float4(bb[0], bb[0], bb[0], bb[1]);
        ov[ob + 1] = make_float4(bb[1], bb[1], bb[2], bb[2]);
        ov[ob + 2] = make_float4(bb[2], bb[3], bb[3], bb[3]);
    }
}

extern "C" void kernel_launch(void* const* d_in, const int* in_sizes, int n_in,
                              void* d_out, int out_size, void* d_ws, size_t ws_size,
                              hipStream_t stream) {
    const float* x = (const float*)d_in[0];
    float* out = (float*)d_out;
    uint8_t* ws = (uint8_t*)d_ws;

    // ws: [0,512) thr f64 | [512,768) bidx i32 | [1024,66560) mm_part f64 |
    //     [66560, 66560+2MiB) hist_part u32 | [2163712, +16MiB) idx4 u8-packed
    double*   thr       = (double*)(ws);
    int*      bidx      = (int*)(ws + 512);
    double*   mm_part   = (double*)(ws + 1024);
    unsigned* hist_part = (unsigned*)(ws + 66560);
    unsigned* idx4      = (unsigned*)(ws + 2163712);
    const bool use_idx = ws_size >= (size_t)2163712 + (size_t)NIMG * HW;

    k_minmax<<<NIMG * MMB, 256, 0, stream>>>(x, mm_part);
    if (use_idx) k_hist<true ><<<NIMG * HB, 256, 0, stream>>>(x, mm_part, hist_part, idx4);
    else         k_hist<false><<<NIMG * HB, 256, 0, stream>>>(x, mm_part, hist_part, nullptr);
    k_otsu<<<NIMG, 256, 0, stream>>>(hist_part, mm_part, thr, bidx);
    if (use_idx) k_binarize<true ><<<NIMG * MMB, 256, 0, stream>>>(x, idx4, thr, bidx, out);
    else         k_binarize<false><<<NIMG * MMB, 256, 0, stream>>>(x, nullptr, thr, bidx, out);
}

// Round 6
// 147.134 us; speedup vs baseline: 1.1604x; 1.1604x over previous
//
#include <hip/hip_runtime.h>
#include <stdint.h>

#define NBINS 256
#define HW    (512 * 512)
#define NIMG  64
#define MMB   64   // minmax blocks per image (4 tiles each)
#define HB    32   // hist blocks per image (8 tiles each)
#define RB 0
#define GB 1032
#define BB 2064
#define STW 3096   // SoA staging words (12.4 KB)

// f64 grayscale, exact op order verified bit-exact vs np reference (rounds 3-5):
__device__ __forceinline__ double gray_of(float r, float g, float b) {
    return fma((double)b, (double)0.1140f,
           fma((double)g, (double)0.5870f,
               (double)r * (double)0.2989f));
}

// Stage one 1024-px tile (768 float4, fully lane-coalesced loads) into SoA LDS.
__device__ __forceinline__ void stage3(const float4* __restrict__ xv, int64_t tile4,
                                       float* __restrict__ st, int tid) {
    #pragma unroll
    for (int k = 0; k < 3; ++k) {
        const int q = k * 256 + tid;
        const float4 v = xv[tile4 + q];
        const int f0 = q * 4;
        int p = (int)(((unsigned)f0 * 21846u) >> 16);  // f0/3
        int c = f0 - 3 * p;                            // f0%3
        const float e[4] = {v.x, v.y, v.z, v.w};
        #pragma unroll
        for (int j = 0; j < 4; ++j) {
            const int base = (c == 0) ? RB : ((c == 1) ? GB : BB);
            st[base + p] = e[j];
            if (++c == 3) { c = 0; ++p; }
        }
    }
}

// 64 blocks/img x 4 tiles; per-block min/max partials (no atomics, no init)
__global__ __launch_bounds__(256) void k_minmax(const float* __restrict__ x,
                                                double* __restrict__ mm_part) {
    __shared__ float st[STW];
    __shared__ double smn[4], smx[4];
    const int tid = threadIdx.x;
    const int img = blockIdx.x >> 6;
    const int blk = blockIdx.x & 63;
    const int64_t img4 = (int64_t)img * (HW * 3 / 4);
    const float4* xv = (const float4*)x;
    double mn = 1e300, mx = -1e300;
    for (int it = 0; it < 4; ++it) {
        stage3(xv, img4 + (int64_t)(blk * 4 + it) * 768, st, tid);
        __syncthreads();
        const float4 R = *(const float4*)&st[RB + 4 * tid];
        const float4 G = *(const float4*)&st[GB + 4 * tid];
        const float4 B = *(const float4*)&st[BB + 4 * tid];
        const double g0 = gray_of(R.x, G.x, B.x), g1 = gray_of(R.y, G.y, B.y),
                     g2 = gray_of(R.z, G.z, B.z), g3 = gray_of(R.w, G.w, B.w);
        mn = fmin(mn, fmin(fmin(g0, g1), fmin(g2, g3)));
        mx = fmax(mx, fmax(fmax(g0, g1), fmax(g2, g3)));
        __syncthreads();
    }
    #pragma unroll
    for (int off = 32; off; off >>= 1) {
        mn = fmin(mn, __shfl_xor(mn, off));
        mx = fmax(mx, __shfl_xor(mx, off));
    }
    if ((tid & 63) == 0) { smn[tid >> 6] = mn; smx[tid >> 6] = mx; }
    __syncthreads();
    if (tid == 0) {
        mn = fmin(fmin(smn[0], smn[1]), fmin(smn[2], smn[3]));
        mx = fmax(fmax(smx[0], smx[1]), fmax(smx[2], smx[3]));
        mm_part[(img * MMB + blk) * 2 + 0] = mn;
        mm_part[(img * MMB + blk) * 2 + 1] = mx;
    }
}

// wave-0 reduce of the 64 min/max partials (exact; order-insensitive)
__device__ __forceinline__ void mm_reduce(const double* __restrict__ mm_part, int img,
                                          int tid, double* __restrict__ sdm) {
    if (tid < 64) {
        double mn = mm_part[(img * MMB + tid) * 2 + 0];
        double mx = mm_part[(img * MMB + tid) * 2 + 1];
        #pragma unroll
        for (int off = 32; off; off >>= 1) {
            mn = fmin(mn, __shfl_xor(mn, off));
            mx = fmax(mx, __shfl_xor(mx, off));
        }
        if (tid == 0) { sdm[0] = mn; sdm[1] = mx; }
    }
}

// 32 blocks/img x 8 tiles: histogram partials + packed u8 bin-index emit
template <bool WIDX>
__global__ __launch_bounds__(256) void k_hist(const float* __restrict__ x,
        const double* __restrict__ mm_part,
        unsigned* __restrict__ hist_part, unsigned* __restrict__ idx4) {
    __shared__ float st[STW];
    __shared__ unsigned lh[NBINS];
    __shared__ double sdm[2];
    const int tid = threadIdx.x;
    const int img = blockIdx.x >> 5;
    const int blk = blockIdx.x & 31;
    lh[tid] = 0u;
    mm_reduce(mm_part, img, tid, sdm);
    __syncthreads();
    const double mn = sdm[0];
    const double scale = 256.0 / fmax(__dsub_rn(sdm[1], mn), 1e-12);
    const int64_t img4 = (int64_t)img * (HW * 3 / 4);
    const float4* xv = (const float4*)x;
    for (int it = 0; it < 8; ++it) {
        stage3(xv, img4 + (int64_t)(blk * 8 + it) * 768, st, tid);
        __syncthreads();
        const float4 R = *(const float4*)&st[RB + 4 * tid];
        const float4 G = *(const float4*)&st[GB + 4 * tid];
        const float4 B = *(const float4*)&st[BB + 4 * tid];
        const double g[4] = {gray_of(R.x, G.x, B.x), gray_of(R.y, G.y, B.y),
                             gray_of(R.z, G.z, B.z), gray_of(R.w, G.w, B.w)};
        unsigned pack = 0;
        #pragma unroll
        for (int j = 0; j < 4; ++j) {
            int id = (int)__dmul_rn(__dsub_rn(g[j], mn), scale);  // trunc = astype(int32)
            id = id < 0 ? 0 : (id > 255 ? 255 : id);
            atomicAdd(&lh[id], 1u);
            pack |= (unsigned)id << (8 * j);
        }
        if (WIDX) idx4[img * (HW / 4) + (blk * 8 + it) * 256 + tid] = pack;
        __syncthreads();
    }
    hist_part[(img * HB + blk) * NBINS + tid] = lh[tid];
}

// one 256-thread block per image; integer partial-sum + bit-exact serial f64 Otsu
__global__ void k_otsu(const unsigned* __restrict__ hist_part,
                       const double* __restrict__ mm_part,
                       double* __restrict__ thr, int* __restrict__ bidx) {
    __shared__ double h[NBINS], w2s[NBINS], m2s[NBINS], vv[NBINS];
    __shared__ double sdm[2];
    const int img = blockIdx.x, t = threadIdx.x;
    mm_reduce(mm_part, img, t, sdm);
    unsigned hu = 0;
    for (int b = 0; b < HB; ++b) hu += hist_part[(img * HB + b) * NBINS + t];  // exact int sum
    h[t] = (double)hu;
    __syncthreads();
    const double mn   = sdm[0];
    const double rng  = fmax(__dsub_rn(sdm[1], mn), 1e-12);
    const double step = rng / 256.0;
    double w1 = 0.0, hc1 = 0.0;
    for (int j = 0; j <= t; ++j) {
        const double c = __dadd_rn(mn, __dmul_rn((double)j + 0.5, step));
        w1  = __dadd_rn(w1, h[j]);
        hc1 = __dadd_rn(hc1, __dmul_rn(h[j], c));
    }
    const double m1 = hc1 / fmax(w1, 1e-12);
    double w2 = 0.0, hc2 = 0.0;
    for (int j = NBINS - 1; j >= t; --j) {
        const double c = __dadd_rn(mn, __dmul_rn((double)j + 0.5, step));
        w2  = __dadd_rn(w2, h[j]);
        hc2 = __dadd_rn(hc2, __dmul_rn(h[j], c));
    }
    w2s[t] = w2;
    m2s[t] = hc2 / fmax(w2, 1e-12);
    __syncthreads();
    if (t < NBINS - 1) {
        const double d = __dsub_rn(m1, m2s[t + 1]);
        vv[t] = __dmul_rn(__dmul_rn(w1, w2s[t + 1]), __dmul_rn(d, d));
    }
    __syncthreads();
    if (t == 0) {
        double best = -1.0; int bi = 0;
        for (int i = 0; i < NBINS - 1; ++i)
            if (vv[i] > best) { best = vv[i]; bi = i; }   // first-occurrence argmax
        thr[img]  = __dadd_rn(mn, __dmul_rn((double)bi + 0.5, step));
        bidx[img] = bi;
    }
}

// 64 blocks/img x 4 tiles: binarize + channel-replicate via LDS broadcast.
// Output stores are q = k*256+tid -> 16 B/lane stride, fully coalesced
// (round-5's register version used 48 B/lane stride stores = the slow pattern).
template <bool UIDX>
__global__ __launch_bounds__(256) void k_binarize(const float* __restrict__ x,
        const unsigned* __restrict__ idx4,
        const double* __restrict__ thr, const int* __restrict__ bidx,
        float* __restrict__ out) {
    __shared__ float st[STW];        // only used when !UIDX
    __shared__ float bst[1024];
    const int tid = threadIdx.x;
    const int img = blockIdx.x >> 6;
    const int blk = blockIdx.x & 63;
    const double T = thr[img];
    const int bi = UIDX ? bidx[img] : 0;
    const int64_t img4 = (int64_t)img * (HW * 3 / 4);
    const float4* xv = (const float4*)x;
    float4* ov = (float4*)out;
    for (int it = 0; it < 4; ++it) {
        const int tl = blk * 4 + it;
        float bb[4];
        if (UIDX) {
            const unsigned pk = idx4[img * (HW / 4) + tl * 256 + tid];
            #pragma unroll
            for (int j = 0; j < 4; ++j) {
                const int id = (pk >> (8 * j)) & 255;
                float r;
                if (id > bi)      r = 255.f;
                else if (id < bi) r = 0.f;
                else {  // rare (~0.4%): boundary bin, recompute exact gray
                    const int64_t p = (int64_t)img * HW + (int64_t)tl * 1024 + 4 * tid + j;
                    const double g = gray_of(x[3 * p], x[3 * p + 1], x[3 * p + 2]);
                    r = (g > T) ? 255.f : 0.f;
                }
                bb[j] = r;
            }
        } else {
            stage3(xv, img4 + (int64_t)tl * 768, st, tid);
            __syncthreads();
            const float4 R = *(const float4*)&st[RB + 4 * tid];
            const float4 G = *(const float4*)&st[GB + 4 * tid];
            const float4 B = *(const float4*)&st[BB + 4 * tid];
            bb[0] = (gray_of(R.x, G.x, B.x) > T) ? 255.f : 0.f;
            bb[1] = (gray_of(R.y, G.y, B.y) > T) ? 255.f : 0.f;
            bb[2] = (gray_of(R.z, G.z, B.z) > T) ? 255.f : 0.f;
            bb[3] = (gray_of(R.w, G.w, B.w) > T) ? 255.f : 0.f;
        }
        *(float4*)&bst[4 * tid] = make_float4(bb[0], bb[1], bb[2], bb[3]);
        __syncthreads();
        const int64_t ob4 = img4 + (int64_t)tl * 768;
        #pragma unroll
        for (int k = 0; k < 3; ++k) {
            const int q  = k * 256 + tid;
            const int p0 = (int)(((unsigned)(q * 4) * 21846u) >> 16);   // (4q)/3
            const int m  = q - 3 * (int)(((unsigned)q * 21846u) >> 16); // q%3
            const float lo = bst[p0];
            const float hi = bst[p0 + 1 < 1024 ? p0 + 1 : 1023];
            float4 o;
            o.x = lo;
            o.y = (m + 1 >= 3) ? hi : lo;
            o.z = (m + 2 >= 3) ? hi : lo;
            o.w = (m + 3 >= 3) ? hi : lo;
            ov[ob4 + q] = o;
        }
        __syncthreads();   // bst/st reusable next tile
    }
}

extern "C" void kernel_launch(void* const* d_in, const int* in_sizes, int n_in,
                              void* d_out, int out_size, void* d_ws, size_t ws_size,
                              hipStream_t stream) {
    const float* x = (const float*)d_in[0];
    float* out = (float*)d_out;
    uint8_t* ws = (uint8_t*)d_ws;

    // ws: [0,512) thr f64 | [512,768) bidx i32 | [1024,66560) mm_part f64 |
    //     [66560, +2MiB) hist_part u32 | [2163712, +16MiB) idx4 u8-packed
    double*   thr       = (double*)(ws);
    int*      bidx      = (int*)(ws + 512);
    double*   mm_part   = (double*)(ws + 1024);
    unsigned* hist_part = (unsigned*)(ws + 66560);
    unsigned* idx4      = (unsigned*)(ws + 2163712);
    const bool use_idx = ws_size >= (size_t)2163712 + (size_t)NIMG * HW;

    k_minmax<<<NIMG * MMB, 256, 0, stream>>>(x, mm_part);
    if (use_idx) k_hist<true ><<<NIMG * HB, 256, 0, stream>>>(x, mm_part, hist_part, idx4);
    else         k_hist<false><<<NIMG * HB, 256, 0, stream>>>(x, mm_part, hist_part, nullptr);
    k_otsu<<<NIMG, 256, 0, stream>>>(hist_part, mm_part, thr, bidx);
    if (use_idx) k_binarize<true ><<<NIMG * MMB, 256, 0, stream>>>(x, idx4, thr, bidx, out);
    else         k_binarize<false><<<NIMG * MMB, 256, 0, stream>>>(x, nullptr, thr, bidx, out);
}

// Round 7
// 136.978 us; speedup vs baseline: 1.2465x; 1.0741x over previous
//
#include <hip/hip_runtime.h>
#include <stdint.h>

#define NBINS 256
#define HW    (512 * 512)
#define NIMG  64
#define MMB   64   // minmax/binarize blocks per image (4 tiles each)
#define HB    32   // hist blocks per image (8 tiles each)
#define RB 0
#define GB 1032
#define BB 2064
#define STW 3096   // SoA staging words (12.4 KB)
#define FINV 0.00390625  // 2^-8, exact

// f64 grayscale, exact op order verified bit-exact vs np reference (rounds 3-6):
__device__ __forceinline__ double gray_of(float r, float g, float b) {
    return fma((double)b, (double)0.1140f,
           fma((double)g, (double)0.5870f,
               (double)r * (double)0.2989f));
}

// Stage one 1024-px tile (768 float4, fully lane-coalesced loads) into SoA LDS.
__device__ __forceinline__ void stage3(const float4* __restrict__ xv, int64_t tile4,
                                       float* __restrict__ st, int tid) {
    #pragma unroll
    for (int k = 0; k < 3; ++k) {
        const int q = k * 256 + tid;
        const float4 v = xv[tile4 + q];
        const int f0 = q * 4;
        int p = (int)(((unsigned)f0 * 21846u) >> 16);  // f0/3
        int c = f0 - 3 * p;                            // f0%3
        const float e[4] = {v.x, v.y, v.z, v.w};
        #pragma unroll
        for (int j = 0; j < 4; ++j) {
            const int base = (c == 0) ? RB : ((c == 1) ? GB : BB);
            st[base + p] = e[j];
            if (++c == 3) { c = 0; ++p; }
        }
    }
}

// K1: 64 blocks/img x 4 tiles; min/max partials + u16 fine-index emit.
// fid = trunc(g*256.0). *256 is a power-of-two scale -> EXACT in f64, so
// g is provably in [fid/256, (fid+1)/256) with exact f64 endpoints.
template <bool WF>
__global__ __launch_bounds__(256) void k_minmax(const float* __restrict__ x,
                                                double* __restrict__ mm_part,
                                                unsigned long long* __restrict__ fid4) {
    __shared__ float st[STW];
    __shared__ double smn[4], smx[4];
    const int tid = threadIdx.x;
    const int img = blockIdx.x >> 6;
    const int blk = blockIdx.x & 63;
    const int64_t img4 = (int64_t)img * (HW * 3 / 4);
    const float4* xv = (const float4*)x;
    double mn = 1e300, mx = -1e300;
    for (int it = 0; it < 4; ++it) {
        const int tl = blk * 4 + it;
        stage3(xv, img4 + (int64_t)tl * 768, st, tid);
        __syncthreads();
        const float4 R = *(const float4*)&st[RB + 4 * tid];
        const float4 G = *(const float4*)&st[GB + 4 * tid];
        const float4 B = *(const float4*)&st[BB + 4 * tid];
        const double g0 = gray_of(R.x, G.x, B.x), g1 = gray_of(R.y, G.y, B.y),
                     g2 = gray_of(R.z, G.z, B.z), g3 = gray_of(R.w, G.w, B.w);
        mn = fmin(mn, fmin(fmin(g0, g1), fmin(g2, g3)));
        mx = fmax(mx, fmax(fmax(g0, g1), fmax(g2, g3)));
        if (WF) {
            const unsigned long long f0 = (unsigned long long)(unsigned)(g0 * 256.0);
            const unsigned long long f1 = (unsigned long long)(unsigned)(g1 * 256.0);
            const unsigned long long f2 = (unsigned long long)(unsigned)(g2 * 256.0);
            const unsigned long long f3 = (unsigned long long)(unsigned)(g3 * 256.0);
            fid4[img * (HW / 4) + tl * 256 + tid] = f0 | (f1 << 16) | (f2 << 32) | (f3 << 48);
        }
        __syncthreads();
    }
    #pragma unroll
    for (int off = 32; off; off >>= 1) {
        mn = fmin(mn, __shfl_xor(mn, off));
        mx = fmax(mx, __shfl_xor(mx, off));
    }
    if ((tid & 63) == 0) { smn[tid >> 6] = mn; smx[tid >> 6] = mx; }
    __syncthreads();
    if (tid == 0) {
        mn = fmin(fmin(smn[0], smn[1]), fmin(smn[2], smn[3]));
        mx = fmax(fmax(smx[0], smx[1]), fmax(smx[2], smx[3]));
        mm_part[(img * MMB + blk) * 2 + 0] = mn;
        mm_part[(img * MMB + blk) * 2 + 1] = mx;
    }
}

// wave-0 reduce of the 64 min/max partials (exact; order-insensitive)
__device__ __forceinline__ void mm_reduce(const double* __restrict__ mm_part, int img,
                                          int tid, double* __restrict__ sdm) {
    if (tid < 64) {
        double mn = mm_part[(img * MMB + tid) * 2 + 0];
        double mx = mm_part[(img * MMB + tid) * 2 + 1];
        #pragma unroll
        for (int off = 32; off; off >>= 1) {
            mn = fmin(mn, __shfl_xor(mn, off));
            mx = fmax(mx, __shfl_xor(mx, off));
        }
        if (tid == 0) { sdm[0] = mn; sdm[1] = mx; }
    }
}

__device__ __forceinline__ int bin_of(double g, double mn, double s) {
    int id = (int)__dmul_rn(__dsub_rn(g, mn), s);  // trunc = astype(int32)
    return id < 0 ? 0 : (id > 255 ? 255 : id);
}

// K2: 32 blocks/img x 8 tiles: histogram from u16 fid (33 MB instead of 201 MB).
// fl((g-mn))*s and trunc are monotone -> if both exact bracket endpoints map to
// the same bin, the bin is exact; else gather-recompute (~0.4% of pixels).
template <bool UF>
__global__ __launch_bounds__(256) void k_hist(const unsigned long long* __restrict__ fid4,
        const float* __restrict__ x, const double* __restrict__ mm_part,
        unsigned* __restrict__ hist_part) {
    __shared__ float st[STW];        // only used when !UF
    __shared__ unsigned lh[NBINS];
    __shared__ double sdm[2];
    const int tid = threadIdx.x;
    const int img = blockIdx.x >> 5;
    const int blk = blockIdx.x & 31;
    lh[tid] = 0u;
    mm_reduce(mm_part, img, tid, sdm);
    __syncthreads();
    const double mn = sdm[0];
    const double s  = 256.0 / fmax(__dsub_rn(sdm[1], mn), 1e-12);
    const int64_t img4 = (int64_t)img * (HW * 3 / 4);
    const float4* xv = (const float4*)x;
    for (int it = 0; it < 8; ++it) {
        const int tl = blk * 8 + it;
        if (UF) {
            const unsigned long long pk = fid4[img * (HW / 4) + tl * 256 + tid];
            #pragma unroll
            for (int j = 0; j < 4; ++j) {
                const unsigned f = (unsigned)(pk >> (16 * j)) & 0xFFFFu;
                const double glo = (double)f * FINV;          // exact
                const double ghi = (double)(f + 1) * FINV;    // exact
                const int clo = bin_of(glo, mn, s);
                const int chi = bin_of(ghi, mn, s);
                int id;
                if (clo == chi) id = clo;
                else {  // boundary fine-bin: recompute exact gray (rare)
                    const int64_t p = (int64_t)img * HW + (int64_t)tl * 1024 + 4 * tid + j;
                    id = bin_of(gray_of(x[3 * p], x[3 * p + 1], x[3 * p + 2]), mn, s);
                }
                atomicAdd(&lh[id], 1u);
            }
        } else {
            stage3(xv, img4 + (int64_t)tl * 768, st, tid);
            __syncthreads();
            const float4 R = *(const float4*)&st[RB + 4 * tid];
            const float4 G = *(const float4*)&st[GB + 4 * tid];
            const float4 B = *(const float4*)&st[BB + 4 * tid];
            atomicAdd(&lh[bin_of(gray_of(R.x, G.x, B.x), mn, s)], 1u);
            atomicAdd(&lh[bin_of(gray_of(R.y, G.y, B.y), mn, s)], 1u);
            atomicAdd(&lh[bin_of(gray_of(R.z, G.z, B.z), mn, s)], 1u);
            atomicAdd(&lh[bin_of(gray_of(R.w, G.w, B.w), mn, s)], 1u);
            __syncthreads();
        }
    }
    __syncthreads();
    hist_part[(img * HB + blk) * NBINS + tid] = lh[tid];
}

// K3: one 256-thread block per image; integer partial-sum + bit-exact f64 Otsu
__global__ void k_otsu(const unsigned* __restrict__ hist_part,
                       const double* __restrict__ mm_part,
                       double* __restrict__ thr) {
    __shared__ double h[NBINS], w2s[NBINS], m2s[NBINS], vv[NBINS];
    __shared__ double sdm[2];
    const int img = blockIdx.x, t = threadIdx.x;
    mm_reduce(mm_part, img, t, sdm);
    unsigned hu = 0;
    for (int b = 0; b < HB; ++b) hu += hist_part[(img * HB + b) * NBINS + t];  // exact int sum
    h[t] = (double)hu;
    __syncthreads();
    const double mn   = sdm[0];
    const double rng  = fmax(__dsub_rn(sdm[1], mn), 1e-12);
    const double step = rng / 256.0;
    double w1 = 0.0, hc1 = 0.0;
    for (int j = 0; j <= t; ++j) {
        const double c = __dadd_rn(mn, __dmul_rn((double)j + 0.5, step));
        w1  = __dadd_rn(w1, h[j]);
        hc1 = __dadd_rn(hc1, __dmul_rn(h[j], c));
    }
    const double m1 = hc1 / fmax(w1, 1e-12);
    double w2 = 0.0, hc2 = 0.0;
    for (int j = NBINS - 1; j >= t; --j) {
        const double c = __dadd_rn(mn, __dmul_rn((double)j + 0.5, step));
        w2  = __dadd_rn(w2, h[j]);
        hc2 = __dadd_rn(hc2, __dmul_rn(h[j], c));
    }
    w2s[t] = w2;
    m2s[t] = hc2 / fmax(w2, 1e-12);
    __syncthreads();
    if (t < NBINS - 1) {
        const double d = __dsub_rn(m1, m2s[t + 1]);
        vv[t] = __dmul_rn(__dmul_rn(w1, w2s[t + 1]), __dmul_rn(d, d));
    }
    __syncthreads();
    if (t == 0) {
        double best = -1.0; int bi = 0;
        for (int i = 0; i < NBINS - 1; ++i)
            if (vv[i] > best) { best = vv[i]; bi = i; }   // first-occurrence argmax
        thr[img] = __dadd_rn(mn, __dmul_rn((double)bi + 0.5, step));
    }
}

// K4: 64 blocks/img x 4 tiles: binarize from fid bracket + LDS-broadcast output
// (coalesced 16 B/lane stores; round 5 proved 48 B/lane stores are 6x slower).
template <bool UF>
__global__ __launch_bounds__(256) void k_binarize(const unsigned long long* __restrict__ fid4,
        const float* __restrict__ x, const double* __restrict__ thr,
        float* __restrict__ out) {
    __shared__ float st[STW];        // only used when !UF
    __shared__ float bst[1024];
    const int tid = threadIdx.x;
    const int img = blockIdx.x >> 6;
    const int blk = blockIdx.x & 63;
    const double T = thr[img];
    const int64_t img4 = (int64_t)img * (HW * 3 / 4);
    const float4* xv = (const float4*)x;
    float4* ov = (float4*)out;
    for (int it = 0; it < 4; ++it) {
        const int tl = blk * 4 + it;
        float bb[4];
        if (UF) {
            const unsigned long long pk = fid4[img * (HW / 4) + tl * 256 + tid];
            #pragma unroll
            for (int j = 0; j < 4; ++j) {
                const unsigned f = (unsigned)(pk >> (16 * j)) & 0xFFFFu;
                const double glo = (double)f * FINV;          // exact, g >= glo
                const double ghi = (double)(f + 1) * FINV;    // exact, g <  ghi
                float r;
                if (glo > T)       r = 255.f;   // g >= glo > T
                else if (ghi <= T) r = 0.f;     // g <  ghi <= T
                else {  // threshold inside fine bin: recompute exact gray (rare)
                    const int64_t p = (int64_t)img * HW + (int64_t)tl * 1024 + 4 * tid + j;
                    const double g = gray_of(x[3 * p], x[3 * p + 1], x[3 * p + 2]);
                    r = (g > T) ? 255.f : 0.f;
                }
                bb[j] = r;
            }
        } else {
            stage3(xv, img4 + (int64_t)tl * 768, st, tid);
            __syncthreads();
            const float4 R = *(const float4*)&st[RB + 4 * tid];
            const float4 G = *(const float4*)&st[GB + 4 * tid];
            const float4 B = *(const float4*)&st[BB + 4 * tid];
            bb[0] = (gray_of(R.x, G.x, B.x) > T) ? 255.f : 0.f;
            bb[1] = (gray_of(R.y, G.y, B.y) > T) ? 255.f : 0.f;
            bb[2] = (gray_of(R.z, G.z, B.z) > T) ? 255.f : 0.f;
            bb[3] = (gray_of(R.w, G.w, B.w) > T) ? 255.f : 0.f;
        }
        *(float4*)&bst[4 * tid] = make_float4(bb[0], bb[1], bb[2], bb[3]);
        __syncthreads();
        const int64_t ob4 = img4 + (int64_t)tl * 768;
        #pragma unroll
        for (int k = 0; k < 3; ++k) {
            const int q  = k * 256 + tid;
            const int p0 = (int)(((unsigned)(q * 4) * 21846u) >> 16);   // (4q)/3
            const int m  = q - 3 * (int)(((unsigned)q * 21846u) >> 16); // q%3
            const float lo = bst[p0];
            const float hi = bst[p0 + 1 < 1024 ? p0 + 1 : 1023];
            float4 o;
            o.x = lo;
            o.y = (m + 1 >= 3) ? hi : lo;
            o.z = (m + 2 >= 3) ? hi : lo;
            o.w = (m + 3 >= 3) ? hi : lo;
            ov[ob4 + q] = o;
        }
        __syncthreads();   // bst/st reusable next tile
    }
}

extern "C" void kernel_launch(void* const* d_in, const int* in_sizes, int n_in,
                              void* d_out, int out_size, void* d_ws, size_t ws_size,
                              hipStream_t stream) {
    const float* x = (const float*)d_in[0];
    float* out = (float*)d_out;
    uint8_t* ws = (uint8_t*)d_ws;

    // ws: [0,512) thr f64 | [1024,66560) mm_part f64 | [66560,2163712) hist_part u32 |
    //     [2163712, +32MiB) fid u16-packed-x4
    double*             thr       = (double*)(ws);
    double*             mm_part   = (double*)(ws + 1024);
    unsigned*           hist_part = (unsigned*)(ws + 66560);
    unsigned long long* fid4      = (unsigned long long*)(ws + 2163712);
    const bool uf = ws_size >= (size_t)2163712 + (size_t)NIMG * HW * 2;

    if (uf) k_minmax<true ><<<NIMG * MMB, 256, 0, stream>>>(x, mm_part, fid4);
    else    k_minmax<false><<<NIMG * MMB, 256, 0, stream>>>(x, mm_part, nullptr);
    if (uf) k_hist<true ><<<NIMG * HB, 256, 0, stream>>>(fid4, x, mm_part, hist_part);
    else    k_hist<false><<<NIMG * HB, 256, 0, stream>>>(nullptr, x, mm_part, hist_part);
    k_otsu<<<NIMG, 256, 0, stream>>>(hist_part, mm_part, thr);
    if (uf) k_binarize<true ><<<NIMG * MMB, 256, 0, stream>>>(fid4, x, thr, out);
    else    k_binarize<false><<<NIMG * MMB, 256, 0, stream>>>(nullptr, x, thr, out);
}